// Round 2
// baseline (398.631 us; speedup 1.0000x reference)
//
#include <hip/hip_runtime.h>
#include <stdint.h>

// CPRLinear: out = x[:, ci] @ dequant(W).T + bias
// B=256, IN=OUT=8192; W_high (8192x2048 int32, tile 128), W_low (8192x6144).
// Strategy: bf16 MFMA GEMM, W dequantized on the fly into LDS, M_TILE=256 so
// W (256MB) streams from HBM exactly once. K-split=4 aligned to high/low
// boundary. Partials in ws + reduce (atomic fallback if ws too small).

#define IN_DIM 8192
#define OUT_DIM 8192
#define BDIM 256
#define NH 2048
#define NL 6144
#define BN 64
#define BK 32
#define KSPLIT 4
#define KSEG (IN_DIM / KSPLIT)   // 2048
#define NSTEP (KSEG / BK)        // 64

typedef __bf16 bf16x8 __attribute__((ext_vector_type(8)));
typedef float f32x4 __attribute__((ext_vector_type(4)));

__device__ __forceinline__ unsigned short bfbits(float f) {
  union { float f; unsigned int u; } v; v.f = f;
  unsigned int u = v.u;
  u += 0x7fffu + ((u >> 16) & 1u);   // RNE
  return (unsigned short)(u >> 16);
}
__device__ __forceinline__ unsigned int pk2(float a, float b) {
  return (unsigned int)bfbits(a) | ((unsigned int)bfbits(b) << 16);
}

// ---------------- gather + bf16 convert: xp[b][k] = bf16(x[b][ci[k]]) ------
extern "C" __global__ void gather_k(const float* __restrict__ x,
                                    const int* __restrict__ ci,
                                    unsigned short* __restrict__ xp) {
  int i4 = blockIdx.x * blockDim.x + threadIdx.x;   // 0..524287
  int b = i4 >> 11;                                  // row (2048 quads/row)
  int k4 = (i4 & 2047) << 2;
  int4 c = *(const int4*)(ci + k4);
  const float* xr = x + (size_t)b * IN_DIM;
  uint2 st;
  st.x = pk2(xr[c.x], xr[c.y]);
  st.y = pk2(xr[c.z], xr[c.w]);
  *(uint2*)(xp + (size_t)b * IN_DIM + k4) = st;
}

// ---------------- GEMM ----------------------------------------------------
// Grid (128, 4): x = n-block (64 cols), y = K-split segment.
// Block 256 thr = 4 waves, each wave computes 64 rows x 64 cols.
// LDS: X dbuf 2x16KB (tile [256][32] bf16, chunk-swizzled), W dbuf 2x4KB.
extern "C" __global__ __launch_bounds__(256, 2)
void gemm_k(const unsigned short* __restrict__ xp,
            const int* __restrict__ Whq, const int* __restrict__ Wlq,
            const float* __restrict__ sh, const float* __restrict__ zh,
            const float* __restrict__ sl, const float* __restrict__ zl,
            const float* __restrict__ bias,
            float* __restrict__ outp,
            int use_atomic)
{
  __shared__ char smem[2 * 16384 + 2 * 4096];   // 40KB
  const int t = threadIdx.x;
  const int lane = t & 63;
  const int wv = t >> 6;
  const int nblk = blockIdx.x;
  const int kh = blockIdx.y;
  const int n0 = nblk * BN;
  const int l15 = lane & 15;
  const int g4 = lane >> 4;

  // X staging: round r, thread t -> row = r*64 + (t>>2), phys chunk = t&3,
  // source chunk = (t&3) ^ (row&3)  (inverse-swizzled source, linear dest)
  const int xr = t >> 2;
  const int xc = (t & 3) ^ (xr & 3);
  const unsigned short* xg0 = xp + (size_t)xr * IN_DIM + (size_t)kh * KSEG + xc * 8;

  // W staging: thread t -> col = t>>2 (of 64), k-chunk wm = t&3 (8 ints)
  const int wcol = t >> 2;
  const int wm = t & 3;
  const int oo = n0 + wcol;
  const int* wb0 = (kh == 0) ? (Whq + (size_t)oo * NH)
                             : (Wlq + (size_t)oo * NL + (size_t)(kh - 1) * KSEG);
  const float* sb = (kh == 0) ? (sh + oo) : (sl + (size_t)(kh - 1) * 16 * OUT_DIM + oo);
  const float* zb = (kh == 0) ? (zh + oo) : (zl + (size_t)(kh - 1) * 16 * OUT_DIM + oo);

  f32x4 acc[4][4];
  {
    float bvj[4];
    #pragma unroll
    for (int j = 0; j < 4; ++j)
      bvj[j] = (kh == 0) ? bias[n0 + j * 16 + l15] : 0.f;
    #pragma unroll
    for (int i = 0; i < 4; ++i)
      #pragma unroll
      for (int j = 0; j < 4; ++j) {
        acc[i][j][0] = bvj[j]; acc[i][j][1] = bvj[j];
        acc[i][j][2] = bvj[j]; acc[i][j][3] = bvj[j];
      }
  }

  int4 q0, q1; float sc, zs;

  auto stage_x = [&](int bx, int s) {
    const unsigned short* g = xg0 + s * BK;
    char* lb = smem + bx * 16384 + wv * 1024;
    #pragma unroll
    for (int r = 0; r < 4; ++r)
      __builtin_amdgcn_global_load_lds(
          (const __attribute__((address_space(1))) void*)(g + (size_t)r * 64 * IN_DIM),
          (__attribute__((address_space(3))) void*)(lb + r * 4096), 16, 0, 0);
  };
  auto stage_w_load = [&](int s) {
    const int* p = wb0 + s * BK + wm * 8;
    q0 = *(const int4*)p;
    q1 = *(const int4*)(p + 4);
    float s_ = sb[(s >> 2) * OUT_DIM];
    float z_ = zb[(s >> 2) * OUT_DIM];
    sc = s_; zs = z_ * s_;
  };
  auto stage_w_write = [&](int bx) {
    uint4 d;
    d.x = pk2((float)q0.x * sc - zs, (float)q0.y * sc - zs);
    d.y = pk2((float)q0.z * sc - zs, (float)q0.w * sc - zs);
    d.z = pk2((float)q1.x * sc - zs, (float)q1.y * sc - zs);
    d.w = pk2((float)q1.z * sc - zs, (float)q1.w * sc - zs);
    char* wb = smem + 32768 + bx * 4096;
    *(uint4*)(wb + wcol * 64 + ((wm ^ (wcol & 3)) * 16)) = d;
  };
  auto compute = [&](int bx) {
    const char* xb = smem + bx * 16384;
    const char* wbuf = smem + 32768 + bx * 4096;
    bf16x8 a[4], b[4];
    #pragma unroll
    for (int i = 0; i < 4; ++i) {
      int row = wv * 64 + i * 16 + l15;
      int ch = g4 ^ (row & 3);
      a[i] = *(const bf16x8*)(xb + row * 64 + ch * 16);
    }
    #pragma unroll
    for (int j = 0; j < 4; ++j) {
      int col = j * 16 + l15;
      int ch = g4 ^ (col & 3);
      b[j] = *(const bf16x8*)(wbuf + col * 64 + ch * 16);
    }
    #pragma unroll
    for (int i = 0; i < 4; ++i)
      #pragma unroll
      for (int j = 0; j < 4; ++j)
        acc[i][j] = __builtin_amdgcn_mfma_f32_16x16x32_bf16(a[i], b[j], acc[i][j], 0, 0, 0);
  };

  // prologue
  stage_x(0, 0);
  stage_w_load(0);
  stage_w_write(0);
  __syncthreads();

  #pragma unroll 1
  for (int s = 0; s < NSTEP; s += 2) {
    stage_x(1, s + 1);
    stage_w_load(s + 1);
    compute(0);
    stage_w_write(1);
    __syncthreads();
    if (s + 2 < NSTEP) { stage_x(0, s + 2); stage_w_load(s + 2); }
    compute(1);
    if (s + 2 < NSTEP) stage_w_write(0);
    __syncthreads();
  }

  // epilogue: C/D mapping col=lane&15, row=(lane>>4)*4+reg
  if (use_atomic) {
    #pragma unroll
    for (int i = 0; i < 4; ++i) {
      int row0 = wv * 64 + i * 16 + g4 * 4;
      #pragma unroll
      for (int j = 0; j < 4; ++j) {
        int col = n0 + j * 16 + l15;
        #pragma unroll
        for (int r = 0; r < 4; ++r)
          atomicAdd(&outp[(size_t)(row0 + r) * OUT_DIM + col], acc[i][j][r]);
      }
    }
  } else {
    float* pp = outp + (size_t)kh * ((size_t)BDIM * OUT_DIM);
    #pragma unroll
    for (int i = 0; i < 4; ++i) {
      int row0 = wv * 64 + i * 16 + g4 * 4;
      #pragma unroll
      for (int j = 0; j < 4; ++j) {
        int col = n0 + j * 16 + l15;
        #pragma unroll
        for (int r = 0; r < 4; ++r)
          pp[(size_t)(row0 + r) * OUT_DIM + col] = acc[i][j][r];
      }
    }
  }
}

// ---------------- reduce: out = sum of 4 partials (bias folded into kh=0) --
extern "C" __global__ void reduce_k(const float* __restrict__ part,
                                    float* __restrict__ out) {
  int i4 = blockIdx.x * blockDim.x + threadIdx.x;   // 0..524287
  size_t off = (size_t)i4 * 4;
  const size_t S = (size_t)BDIM * OUT_DIM;
  float4 p0 = *(const float4*)(part + off);
  float4 p1 = *(const float4*)(part + off + S);
  float4 p2 = *(const float4*)(part + off + 2 * S);
  float4 p3 = *(const float4*)(part + off + 3 * S);
  float4 r;
  r.x = p0.x + p1.x + p2.x + p3.x;
  r.y = p0.y + p1.y + p2.y + p3.y;
  r.z = p0.z + p1.z + p2.z + p3.z;
  r.w = p0.w + p1.w + p2.w + p3.w;
  *(float4*)(out + off) = r;
}

extern "C" void kernel_launch(void* const* d_in, const int* in_sizes, int n_in,
                              void* d_out, int out_size, void* d_ws, size_t ws_size,
                              hipStream_t stream) {
  const float* x   = (const float*)d_in[0];
  const int* Whq   = (const int*)d_in[1];
  const int* Wlq   = (const int*)d_in[2];
  const float* sh  = (const float*)d_in[3];
  const float* zh  = (const float*)d_in[4];
  const float* sl  = (const float*)d_in[5];
  const float* zl  = (const float*)d_in[6];
  const float* bias = (const float*)d_in[7];
  const int* ci    = (const int*)d_in[8];
  float* out = (float*)d_out;

  unsigned short* xp = (unsigned short*)d_ws;
  const size_t XP_BYTES = (size_t)BDIM * IN_DIM * 2;                 // 4MB
  const size_t PART_BYTES = (size_t)KSPLIT * BDIM * OUT_DIM * 4;     // 32MB
  bool have_ws = ws_size >= XP_BYTES + PART_BYTES;

  gather_k<<<dim3(2048), dim3(256), 0, stream>>>(x, ci, xp);

  dim3 gg(OUT_DIM / BN, KSPLIT);
  if (have_ws) {
    float* part = (float*)((char*)d_ws + XP_BYTES);
    gemm_k<<<gg, dim3(256), 0, stream>>>(xp, Whq, Wlq, sh, zh, sl, zl, bias, part, 0);
    reduce_k<<<dim3(2048), dim3(256), 0, stream>>>(part, out);
  } else {
    hipMemsetAsync(d_out, 0, (size_t)out_size * sizeof(float), stream);
    gemm_k<<<gg, dim3(256), 0, stream>>>(xp, Whq, Wlq, sh, zh, sl, zl, bias, out, 1);
  }
}

// Round 3
// 388.104 us; speedup vs baseline: 1.0271x; 1.0271x over previous
//
#include <hip/hip_runtime.h>
#include <stdint.h>

// CPRLinear: out = x[:, ci] @ dequant(W).T + bias
// B=256, IN=OUT=8192; W_high (8192x2048 int32, tile 128), W_low (8192x6144).
// bf16 MFMA GEMM, W dequantized on the fly into LDS, M_TILE=256 so W (256MB)
// streams from HBM exactly once. K-split=4 aligned to high/low boundary.
// R2 fix: latency-bound (17.9% HBM, 2 full vmcnt(0) drains per step).
// -> raw s_barrier + counted vmcnt(2) (W prefetch stays in flight across
//    barriers), 1 barrier/step, scales preloaded to LDS.

#define IN_DIM 8192
#define OUT_DIM 8192
#define BDIM 256
#define NH 2048
#define NL 6144
#define BN 64
#define BK 32
#define KSPLIT 4
#define KSEG (IN_DIM / KSPLIT)   // 2048
#define NSTEP (KSEG / BK)        // 64
#define NTILE (KSEG / 128)       // 16 scale tiles per segment

// LDS layout (48KB):
//   X  dbuf: 2 x 16384  at [0, 32768)      tile [256 rows][32 k] bf16, chunk-swz
//   W  dbuf: 2 x 4096   at [32768, 40960)  tile [64 cols][32 k] bf16, chunk-swz
//   SC:      [16][64] f32 at [40960, 45056)
//   ZS:      [16][64] f32 at [45056, 49152)  (z*s premultiplied)
#define XOFF 0
#define WOFF 32768
#define SCOFF 40960
#define ZSOFF 45056

typedef __bf16 bf16x8 __attribute__((ext_vector_type(8)));
typedef float f32x4 __attribute__((ext_vector_type(4)));

__device__ __forceinline__ unsigned short bfbits(float f) {
  union { float f; unsigned int u; } v; v.f = f;
  unsigned int u = v.u;
  u += 0x7fffu + ((u >> 16) & 1u);   // RNE
  return (unsigned short)(u >> 16);
}
__device__ __forceinline__ unsigned int pk2(float a, float b) {
  return (unsigned int)bfbits(a) | ((unsigned int)bfbits(b) << 16);
}

// ---------------- gather + bf16 convert: xp[b][k] = bf16(x[b][ci[k]]) ------
extern "C" __global__ void gather_k(const float* __restrict__ x,
                                    const int* __restrict__ ci,
                                    unsigned short* __restrict__ xp) {
  int i4 = blockIdx.x * blockDim.x + threadIdx.x;   // 0..524287
  int b = i4 >> 11;                                  // row (2048 quads/row)
  int k4 = (i4 & 2047) << 2;
  int4 c = *(const int4*)(ci + k4);
  const float* xr = x + (size_t)b * IN_DIM;
  uint2 st;
  st.x = pk2(xr[c.x], xr[c.y]);
  st.y = pk2(xr[c.z], xr[c.w]);
  *(uint2*)(xp + (size_t)b * IN_DIM + k4) = st;
}

// ---------------- GEMM ----------------------------------------------------
extern "C" __global__ __launch_bounds__(256, 2)
void gemm_k(const unsigned short* __restrict__ xp,
            const int* __restrict__ Whq, const int* __restrict__ Wlq,
            const float* __restrict__ sh, const float* __restrict__ zh,
            const float* __restrict__ sl, const float* __restrict__ zl,
            const float* __restrict__ bias,
            float* __restrict__ outp,
            int use_atomic)
{
  __shared__ char smem[49152];
  const int t = threadIdx.x;
  const int lane = t & 63;
  const int wv = t >> 6;
  const int kh = blockIdx.y;
  const int n0 = blockIdx.x * BN;
  const int l15 = lane & 15;
  const int g4 = lane >> 4;

  // X staging: thread t -> row = t>>2 (+64 per round), phys chunk = t&3,
  // source chunk = (t&3) ^ (row&3)  (inverse-swizzled source, linear dest)
  const int xr = t >> 2;
  const int xc = (t & 3) ^ (xr & 3);
  const unsigned short* xg0 = xp + (size_t)xr * IN_DIM + (size_t)kh * KSEG + xc * 8;

  // W staging: thread t -> col = t>>2 (of 64), k-chunk wm = t&3 (8 ints)
  const int wcol = t >> 2;
  const int wm = t & 3;
  const int* wb0 = (kh == 0) ? (Whq + (size_t)(n0 + wcol) * NH)
                             : (Wlq + (size_t)(n0 + wcol) * NL + (size_t)(kh - 1) * KSEG);
  const float* sbase = ((kh == 0) ? sh : sl + (size_t)(kh - 1) * NTILE * OUT_DIM) + n0;
  const float* zbase = ((kh == 0) ? zh : zl + (size_t)(kh - 1) * NTILE * OUT_DIM) + n0;

  f32x4 acc[4][4];
  {
    float bvj[4];
    #pragma unroll
    for (int j = 0; j < 4; ++j)
      bvj[j] = (kh == 0) ? bias[n0 + j * 16 + l15] : 0.f;
    #pragma unroll
    for (int i = 0; i < 4; ++i)
      #pragma unroll
      for (int j = 0; j < 4; ++j) {
        acc[i][j][0] = bvj[j]; acc[i][j][1] = bvj[j];
        acc[i][j][2] = bvj[j]; acc[i][j][3] = bvj[j];
      }
  }

  auto stage_x = [&](int bx, int s) {
    const unsigned short* g = xg0 + s * BK;
    char* lb = smem + XOFF + bx * 16384 + wv * 1024;
    #pragma unroll
    for (int r = 0; r < 4; ++r)
      __builtin_amdgcn_global_load_lds(
          (const __attribute__((address_space(1))) void*)(g + (size_t)r * 64 * IN_DIM),
          (__attribute__((address_space(3))) void*)(lb + r * 4096), 16, 0, 0);
  };
  auto wload = [&](int4& a, int4& b, int s) {
    const int* p = wb0 + s * BK + wm * 8;
    a = *(const int4*)p;
    b = *(const int4*)(p + 4);
  };
  auto wdeq = [&](int bx, int4 a, int4 b, int s) {   // dequant W(tile s) -> wlds[bx]
    int tl = s >> 2;
    float sc = *(const float*)(smem + SCOFF + (tl * 64 + wcol) * 4);
    float zs = *(const float*)(smem + ZSOFF + (tl * 64 + wcol) * 4);
    uint4 d;
    d.x = pk2((float)a.x * sc - zs, (float)a.y * sc - zs);
    d.y = pk2((float)a.z * sc - zs, (float)a.w * sc - zs);
    d.z = pk2((float)b.x * sc - zs, (float)b.y * sc - zs);
    d.w = pk2((float)b.z * sc - zs, (float)b.w * sc - zs);
    *(uint4*)(smem + WOFF + bx * 4096 + wcol * 64 + ((wm ^ (wcol & 3)) * 16)) = d;
  };
  auto compute = [&](int bx) {
    const char* xb = smem + XOFF + bx * 16384;
    const char* wbuf = smem + WOFF + bx * 4096;
    bf16x8 a[4], b[4];
    #pragma unroll
    for (int i = 0; i < 4; ++i) {
      int row = wv * 64 + i * 16 + l15;
      int ch = g4 ^ (row & 3);
      a[i] = *(const bf16x8*)(xb + row * 64 + ch * 16);
    }
    #pragma unroll
    for (int j = 0; j < 4; ++j) {
      int col = j * 16 + l15;
      int ch = g4 ^ (col & 3);
      b[j] = *(const bf16x8*)(wbuf + col * 64 + ch * 16);
    }
    #pragma unroll
    for (int i = 0; i < 4; ++i)
      #pragma unroll
      for (int j = 0; j < 4; ++j)
        acc[i][j] = __builtin_amdgcn_mfma_f32_16x16x32_bf16(a[i], b[j], acc[i][j], 0, 0, 0);
  };

  // ---- prologue: scales->LDS, X0 staged, W0/W1 in regs, tile0 dequanted
  #pragma unroll
  for (int r = 0; r < 4; ++r) {
    int p = t + r * 256;             // (tile,col) pair: tile=p>>6, col=p&63
    float s_ = sbase[(size_t)(p >> 6) * OUT_DIM + (p & 63)];
    float z_ = zbase[(size_t)(p >> 6) * OUT_DIM + (p & 63)];
    *(float*)(smem + SCOFF + p * 4) = s_;
    *(float*)(smem + ZSOFF + p * 4) = z_ * s_;
  }
  stage_x(0, 0);
  int4 qa0, qa1, qb0, qb1;
  wload(qa0, qa1, 0);
  wload(qb0, qb1, 1);
  __syncthreads();                   // one-time full drain: scales+X0 visible
  wdeq(0, qa0, qa1, 0);
  asm volatile("s_waitcnt lgkmcnt(0)" ::: "memory");
  __builtin_amdgcn_s_barrier();

  // ---- main loop: 1 raw barrier/step, W prefetch never drained
  // invariant at even step s: xlds[0],wlds[0] ready; qb=W(s+1) in flight
  #pragma unroll 1
  for (int it = 0; it < 31; ++it) {
    const int s = it * 2;
    // even step s (buf 0)
    __builtin_amdgcn_sched_barrier(0);
    stage_x(1, s + 1);                       // vm: +4 (X(s+1))
    __builtin_amdgcn_sched_barrier(0);
    wload(qa0, qa1, s + 2);                  // vm: +2 (W(s+2))
    __builtin_amdgcn_sched_barrier(0);
    compute(0);
    wdeq(1, qb0, qb1, s + 1);                // auto vmcnt(6): W(s+1) arrived
    asm volatile("s_waitcnt vmcnt(2) lgkmcnt(0)" ::: "memory");  // X landed, W(s+2) in flight
    __builtin_amdgcn_s_barrier();
    // odd step s+1 (buf 1)
    __builtin_amdgcn_sched_barrier(0);
    stage_x(0, s + 2);
    __builtin_amdgcn_sched_barrier(0);
    wload(qb0, qb1, s + 3);
    __builtin_amdgcn_sched_barrier(0);
    compute(1);
    wdeq(0, qa0, qa1, s + 2);
    asm volatile("s_waitcnt vmcnt(2) lgkmcnt(0)" ::: "memory");
    __builtin_amdgcn_s_barrier();
  }
  // step 62 (buf 0): stage X63, no more W loads
  __builtin_amdgcn_sched_barrier(0);
  stage_x(1, 63);
  __builtin_amdgcn_sched_barrier(0);
  compute(0);
  wdeq(1, qb0, qb1, 63);
  asm volatile("s_waitcnt vmcnt(0) lgkmcnt(0)" ::: "memory");
  __builtin_amdgcn_s_barrier();
  // step 63 (buf 1)
  compute(1);

  // ---- epilogue: C/D mapping col=lane&15, row=(lane>>4)*4+reg
  if (use_atomic) {
    #pragma unroll
    for (int i = 0; i < 4; ++i) {
      int row0 = wv * 64 + i * 16 + g4 * 4;
      #pragma unroll
      for (int j = 0; j < 4; ++j) {
        int col = n0 + j * 16 + l15;
        #pragma unroll
        for (int r = 0; r < 4; ++r)
          atomicAdd(&outp[(size_t)(row0 + r) * OUT_DIM + col], acc[i][j][r]);
      }
    }
  } else {
    float* pp = outp + (size_t)kh * ((size_t)BDIM * OUT_DIM);
    #pragma unroll
    for (int i = 0; i < 4; ++i) {
      int row0 = wv * 64 + i * 16 + g4 * 4;
      #pragma unroll
      for (int j = 0; j < 4; ++j) {
        int col = n0 + j * 16 + l15;
        #pragma unroll
        for (int r = 0; r < 4; ++r)
          pp[(size_t)(row0 + r) * OUT_DIM + col] = acc[i][j][r];
      }
    }
  }
}

// ---------------- reduce: out = sum of 4 partials (bias folded into kh=0) --
extern "C" __global__ void reduce_k(const float* __restrict__ part,
                                    float* __restrict__ out) {
  int i4 = blockIdx.x * blockDim.x + threadIdx.x;   // 0..524287
  size_t off = (size_t)i4 * 4;
  const size_t S = (size_t)BDIM * OUT_DIM;
  float4 p0 = *(const float4*)(part + off);
  float4 p1 = *(const float4*)(part + off + S);
  float4 p2 = *(const float4*)(part + off + 2 * S);
  float4 p3 = *(const float4*)(part + off + 3 * S);
  float4 r;
  r.x = p0.x + p1.x + p2.x + p3.x;
  r.y = p0.y + p1.y + p2.y + p3.y;
  r.z = p0.z + p1.z + p2.z + p3.z;
  r.w = p0.w + p1.w + p2.w + p3.w;
  *(float4*)(out + off) = r;
}

extern "C" void kernel_launch(void* const* d_in, const int* in_sizes, int n_in,
                              void* d_out, int out_size, void* d_ws, size_t ws_size,
                              hipStream_t stream) {
  const float* x   = (const float*)d_in[0];
  const int* Whq   = (const int*)d_in[1];
  const int* Wlq   = (const int*)d_in[2];
  const float* sh  = (const float*)d_in[3];
  const float* zh  = (const float*)d_in[4];
  const float* sl  = (const float*)d_in[5];
  const float* zl  = (const float*)d_in[6];
  const float* bias = (const float*)d_in[7];
  const int* ci    = (const int*)d_in[8];
  float* out = (float*)d_out;

  unsigned short* xp = (unsigned short*)d_ws;
  const size_t XP_BYTES = (size_t)BDIM * IN_DIM * 2;                 // 4MB
  const size_t PART_BYTES = (size_t)KSPLIT * BDIM * OUT_DIM * 4;     // 32MB
  bool have_ws = ws_size >= XP_BYTES + PART_BYTES;

  gather_k<<<dim3(2048), dim3(256), 0, stream>>>(x, ci, xp);

  dim3 gg(OUT_DIM / BN, KSPLIT);
  if (have_ws) {
    float* part = (float*)((char*)d_ws + XP_BYTES);
    gemm_k<<<gg, dim3(256), 0, stream>>>(xp, Whq, Wlq, sh, zh, sl, zl, bias, part, 0);
    reduce_k<<<dim3(2048), dim3(256), 0, stream>>>(part, out);
  } else {
    hipMemsetAsync(d_out, 0, (size_t)out_size * sizeof(float), stream);
    gemm_k<<<gg, dim3(256), 0, stream>>>(xp, Whq, Wlq, sh, zh, sl, zl, bias, out, 1);
  }
}